// Round 10
// baseline (12887.709 us; speedup 1.0000x reference)
//
#include <hip/hip_runtime.h>
#include <math.h>

#define BT 256
#define GRID 144

// Problem constants: B=16, T=64, IN=256, H=512, N=256, W=64, R=4, NW=1, OUT=256
#define Bx 16
#define Tt 64

__device__ __forceinline__ float sigm(float v) { return 1.0f / (1.0f + expf(-v)); }
__device__ __forceinline__ float oneplusf(float v) { return 1.0f + ((v > 15.0f) ? v : log1pf(expf(v))); }
__device__ __forceinline__ float4 ld4(const float* p) { return *reinterpret_cast<const float4*>(p); }
__device__ __forceinline__ float2 ld2f(const float* p) { return *reinterpret_cast<const float2*>(p); }

// ---- agent-scope (MALL-coherent) accessors for cross-block data ----
#define SCOPE_A __HIP_MEMORY_SCOPE_AGENT
__device__ __forceinline__ float gld(const float* p) {
    return __hip_atomic_load(p, __ATOMIC_RELAXED, SCOPE_A);
}
__device__ __forceinline__ void gst(float* p, float v) {
    __hip_atomic_store(p, v, __ATOMIC_RELAXED, SCOPE_A);
}
__device__ __forceinline__ float2 gld2(const float* p) {
    union { unsigned long long u; float2 f; } c;
    c.u = __hip_atomic_load(reinterpret_cast<const unsigned long long*>(p), __ATOMIC_RELAXED, SCOPE_A);
    return c.f;
}
__device__ __forceinline__ void gst2(float* p, float a, float b2) {
    union { unsigned long long u; float2 f; } c;
    c.f.x = a; c.f.y = b2;
    __hip_atomic_store(reinterpret_cast<unsigned long long*>(p), c.u, __ATOMIC_RELAXED, SCOPE_A);
}
__device__ __forceinline__ unsigned gldU(const unsigned* p) {
    return __hip_atomic_load(p, __ATOMIC_RELAXED, SCOPE_A);
}
__device__ __forceinline__ void gstU(unsigned* p, unsigned v) {
    __hip_atomic_store(p, v, __ATOMIC_RELAXED, SCOPE_A);
}

// ---- contention-free monotonic flag barrier; flags and gen on separate lines ----
__device__ __attribute__((aligned(128))) unsigned int g_flags[GRID];
__device__ __attribute__((aligned(128))) unsigned int g_gen = 0;

__device__ __forceinline__ void gsync(unsigned tgt) {
    asm volatile("" ::: "memory");
    __builtin_amdgcn_s_waitcnt(0);
    __syncthreads();
    const int tid = threadIdx.x;
    if (blockIdx.x == 0) {
        if (tid < GRID) {
            if (tid == 0) gstU(&g_flags[0], tgt);
            while (gldU(&g_flags[tid]) < tgt) __builtin_amdgcn_s_sleep(1);
        }
        __syncthreads();
        if (tid == 0) gstU(&g_gen, tgt);
    } else {
        if (tid == 0) {
            gstU(&g_flags[blockIdx.x], tgt);
            while (gldU(&g_gen) < tgt) __builtin_amdgcn_s_sleep(1);
        }
        __syncthreads();
    }
    asm volatile("" ::: "memory");
}

// ---- workspace layout (float offsets) — identical to round 5/7 ----
#define ZERO_FLOATS 1376256

__global__ __launch_bounds__(BT)
void k_dnc(const float* __restrict__ x,
           const float* __restrict__ W_ih, const float* __restrict__ W_hh,
           const float* __restrict__ b_ih, const float* __restrict__ b_hh,
           const float* __restrict__ W_int, const float* __restrict__ b_int,
           const float* __restrict__ W_out, const float* __restrict__ b_out,
           float* __restrict__ outp, float* __restrict__ ws)
{
    const int bl = blockIdx.x, tid = threadIdx.x;

    float* h0   = ws;
    float* h1   = ws + 8192;
    float* cst  = ws + 16384;    // block-private
    float* Mb   = ws + 24576;    // agent
    float* usg  = ws + 286720;   // block-private (C-blocks)
    float* lnk  = ws + 290816;   // private to D-link blocks (normal cached, L2)
    float* pr0  = ws + 1339392;
    float* pr1  = ws + 1343488;
    float* wrb  = ws + 1347584;
    float* wwb  = ws + 1363968;
    float* rwb  = ws + 1368064;
    float* nrm  = ws + 1372160;
    float* itf  = ws + 1376256;
    float* ers  = ws + 1383792;
    float* wvs  = ws + 1384816;
    float* rso  = ws + 1385840;
    float* mds  = ws + 1385904;
    float* oh   = ws + 1386096;
    float* bwdb = ws + 1402480;
    float* fwdb = ws + 1418864;

    __shared__ __align__(16) float sbig[16576];
    __shared__ __align__(16) float smem[4096];
    __shared__ int s_idx[256];
    __shared__ unsigned s_base;

    if (tid == 0) s_base = gldU(&g_gen);
    __syncthreads();
    unsigned bseq = s_base;

    for (int i = bl * BT + tid; i < ZERO_FLOATS; i += GRID * BT) gst(ws + i, 0.0f);
    gsync(++bseq);

    for (int t = 0; t < Tt; ++t) {
        const float* hr = (t & 1) ? h1 : h0;
        float*       hw = (t & 1) ? h0 : h1;
        const float* pr_r = (t & 1) ? pr1 : pr0;
        float*       pr_w = (t & 1) ? pr0 : pr1;

        // ========== phase A: blocks 0..127 gates GEMM + LSTM; 128..143 finish out[t-1]
        if (bl < 128) {
            {
                const float* xb = x + (size_t)t * (Bx * 256);
                for (int i = tid; i < 2048; i += BT) {
                    int b2 = i >> 7, q = (i & 127) * 2;
                    float2 v = ld2f(xb + b2 * 256 + q);
                    *reinterpret_cast<float2*>(&sbig[b2 * 260 + q]) = v;
                }
                for (int i = tid; i < 2048; i += BT) {
                    int b2 = i >> 7, q = (i & 127) * 2;
                    float2 v = gld2(rwb + b2 * 256 + q);
                    *reinterpret_cast<float2*>(&sbig[4160 + b2 * 260 + q]) = v;
                }
                for (int i = tid; i < 4096; i += BT) {
                    int b2 = i >> 8, q = (i & 255) * 2;
                    float2 v = gld2(hr + b2 * 512 + q);
                    *reinterpret_cast<float2*>(&sbig[8320 + b2 * 516 + q]) = v;
                }
            }
            __syncthreads();
            float* red = smem;
            int pl = tid >> 2, ks = tid & 3;
            int p = bl * 64 + pl;
            int b = p & 15, j = p >> 4;
            const float *w0, *w1, *w2, *w3;
            int kofs = (ks < 2) ? ks * 256 : (ks - 2) * 256;
            if (ks < 2) {
                w0 = W_ih + (j)        * 512 + kofs;
                w1 = W_ih + (j + 512)  * 512 + kofs;
                w2 = W_ih + (j + 1024) * 512 + kofs;
                w3 = W_ih + (j + 1536) * 512 + kofs;
            } else {
                w0 = W_hh + (j)        * 512 + kofs;
                w1 = W_hh + (j + 512)  * 512 + kofs;
                w2 = W_hh + (j + 1024) * 512 + kofs;
                w3 = W_hh + (j + 1536) * 512 + kofs;
            }
            const float* s = (ks == 0) ? &sbig[b * 260]
                           : (ks == 1) ? &sbig[4160 + b * 260]
                           :             &sbig[8320 + b * 516 + (ks - 2) * 256];
            float a0 = 0, a1 = 0, a2 = 0, a3 = 0;
            for (int kk = 0; kk < 256; kk += 4) {
                float4 iv = *reinterpret_cast<const float4*>(s + kk);
                float4 q0 = ld4(w0 + kk);
                a0 += iv.x * q0.x + iv.y * q0.y + iv.z * q0.z + iv.w * q0.w;
                float4 q1 = ld4(w1 + kk);
                a1 += iv.x * q1.x + iv.y * q1.y + iv.z * q1.z + iv.w * q1.w;
                float4 q2 = ld4(w2 + kk);
                a2 += iv.x * q2.x + iv.y * q2.y + iv.z * q2.z + iv.w * q2.w;
                float4 q3 = ld4(w3 + kk);
                a3 += iv.x * q3.x + iv.y * q3.y + iv.z * q3.z + iv.w * q3.w;
            }
            __syncthreads();
            red[pl * 16 + 0 * 4 + ks] = a0;
            red[pl * 16 + 1 * 4 + ks] = a1;
            red[pl * 16 + 2 * 4 + ks] = a2;
            red[pl * 16 + 3 * 4 + ks] = a3;
            __syncthreads();
            if (ks == 0) {
                const float* rp = red + pl * 16;
                float gi = rp[0]  + rp[1]  + rp[2]  + rp[3]  + b_ih[j]        + b_hh[j];
                float gf = rp[4]  + rp[5]  + rp[6]  + rp[7]  + b_ih[j + 512]  + b_hh[j + 512];
                float gg = rp[8]  + rp[9]  + rp[10] + rp[11] + b_ih[j + 1024] + b_hh[j + 1024];
                float go = rp[12] + rp[13] + rp[14] + rp[15] + b_ih[j + 1536] + b_hh[j + 1536];
                float cv = cst[b * 512 + j];
                cv = sigm(gf) * cv + sigm(gi) * tanhf(gg);
                float hv = sigm(go) * tanhf(cv);
                cst[b * 512 + j] = cv;
                gst(hw + b * 512 + j, hv);
            }
        } else if (t > 0) {
            int b = bl - 128;
            if (tid < 128) {
                float2 v = gld2(rwb + b * 256 + tid * 2);
                *reinterpret_cast<float2*>(&smem[tid * 2]) = v;
            }
            __syncthreads();
            int o = tid;
            float acc = b_out[o];
            acc += gld(oh + b * 256 + o) + gld(oh + (16 + b) * 256 + o)
                 + gld(oh + (32 + b) * 256 + o) + gld(oh + (48 + b) * 256 + o);
            const float* wrow = W_out + o * 768 + 512;
            for (int k = 0; k < 256; k += 4) {
                float4 w4 = ld4(wrow + k);
                float4 s4 = *reinterpret_cast<const float4*>(&smem[k]);
                acc += s4.x * w4.x + s4.y * w4.y + s4.z * w4.z + s4.w * w4.w;
            }
            outp[((size_t)(t - 1) * Bx + b) * 256 + o] = acc;
        }
        gsync(++bseq);

        // ========== phase BC (merged): blocks 0..15 itf + interface/usage/rank/alloc/cw/ww/prec;
        //            blocks 16..79 oh partials
        if (bl < 16) {
            const int b = bl;
            float* s_keys = smem;          // 256
            float* s_cw   = smem + 256;    // 256
            float* s_al   = smem + 512;    // 256
            float* s_tmp  = smem + 768;    // 256
            float* s_wk   = smem + 1024;   // 64
            float* s_sc   = smem + 1088;   // 8
            float* s_h    = smem + 1152;   // 512
            float* s_itf  = smem + 1664;   // 472
            float* s_part = smem + 2176;   // 1024

            for (int i = tid; i < 8192; i += BT) {
                int n = i >> 5, w2 = (i & 31) * 2;
                float2 v = gld2(Mb + (b * 256 + n) * 64 + w2);
                sbig[w2 * 256 + ((n + w2) & 255)] = v.x;
                sbig[(w2 + 1) * 256 + ((n + w2 + 1) & 255)] = v.y;
            }
            {
                float2 v = gld2(hw + b * 512 + tid * 2);
                *reinterpret_cast<float2*>(&s_h[tid * 2]) = v;
            }
            gst(bwdb + b * 1024 + tid, 0.f);
            gst(bwdb + b * 1024 + 256 + tid, 0.f);
            gst(bwdb + b * 1024 + 512 + tid, 0.f);
            gst(bwdb + b * 1024 + 768 + tid, 0.f);
            __syncthreads();

            {
                int jp = tid & 127, kh = tid >> 7;   // kh in {0,1}
                for (int r2 = 0; r2 < 2; ++r2) {
                    int j0 = (r2 * 128 + jp) * 2;
                    float a0 = 0.f, a1 = 0.f;
                    if (j0 < 471) {
                        const float* wc = W_int + j0;
                        for (int k = kh * 256; k < kh * 256 + 256; ++k) {
                            float2 wv = ld2f(wc + k * 471);
                            float hv = s_h[k];
                            a0 += hv * wv.x;
                            a1 += hv * wv.y;
                        }
                    }
                    s_part[kh * 512 + jp * 2]     = a0;
                    s_part[kh * 512 + jp * 2 + 1] = a1;
                    __syncthreads();
                    int j = r2 * 256 + tid;
                    if (j < 471)
                        s_itf[j] = s_part[tid] + s_part[512 + tid] + b_int[j];
                    __syncthreads();
                }
            }
            gst(itf + b * 471 + tid, s_itf[tid]);

            const float* it = s_itf;
            if (tid < 4) {
                float m0 = it[459 + tid * 3], m1 = it[460 + tid * 3], m2 = it[461 + tid * 3];
                float mx3 = fmaxf(m0, fmaxf(m1, m2));
                float e0 = expf(m0 - mx3), e1 = expf(m1 - mx3), e2 = expf(m2 - mx3);
                float inv = 1.f / (e0 + e1 + e2);
                gst(mds + (b * 4 + tid) * 3 + 0, e0 * inv);
                gst(mds + (b * 4 + tid) * 3 + 1, e1 * inv);
                gst(mds + (b * 4 + tid) * 3 + 2, e2 * inv);
                gst(rso + b * 4 + tid, oneplusf(it[256 + tid]));
                s_sc[tid] = sigm(it[453 + tid]);
            }
            if (tid == 4) s_sc[4] = sigm(it[457]);
            if (tid == 5) s_sc[5] = sigm(it[458]);
            if (tid == 6) s_sc[6] = oneplusf(it[324]);
            if (tid < 64) {
                gst(ers + b * 64 + tid, sigm(it[325 + tid]));
                gst(wvs + b * 64 + tid, sigm(it[389 + tid]));
                s_wk[tid] = it[260 + tid];
            }
            __syncthreads();
            if (tid < 64) {
                float v = s_wk[tid] * s_wk[tid];
                for (int o2 = 32; o2 > 0; o2 >>= 1) v += __shfl_down(v, o2);
                if (tid == 0) s_sc[7] = sqrtf(v);
            }
            __syncthreads();
            {
                int n = tid;
                float psi = 1.f;
#pragma unroll
                for (int r = 0; r < 4; r++) psi *= (1.f - s_sc[r] * gld(wrb + b * 1024 + r * 256 + n));
                float wwp = gld(wwb + b * 256 + n);
                float u = usg[b * 256 + n];
                u = (u + wwp - u * wwp) * psi;
                usg[b * 256 + n] = u;
                s_keys[n] = u;
                float dot = 0.f;
                for (int w = 0; w < 64; ++w)
                    dot += sbig[w * 256 + ((n + w) & 255)] * s_wk[w];
                s_cw[n] = s_sc[6] * dot / ((gld(nrm + b * 256 + n) + 1e-6f) * (s_sc[7] + 1e-6f));
            }
            __syncthreads();
            s_tmp[tid] = s_cw[tid];
            __syncthreads();
            for (int s2 = 128; s2 > 0; s2 >>= 1) { if (tid < s2) s_tmp[tid] = fmaxf(s_tmp[tid], s_tmp[tid + s2]); __syncthreads(); }
            float mx = s_tmp[0];
            __syncthreads();
            float ex = expf(s_cw[tid] - mx);
            s_tmp[tid] = ex;
            __syncthreads();
            for (int s2 = 128; s2 > 0; s2 >>= 1) { if (tid < s2) s_tmp[tid] += s_tmp[tid + s2]; __syncthreads(); }
            float cwv = ex / s_tmp[0];
            __syncthreads();
            s_cw[tid] = cwv;

            {
                float myk = s_keys[tid];
                __syncthreads();
                int rank = 0;
                for (int j2 = 0; j2 < 256; ++j2) {
                    float kj = s_keys[j2];
                    rank += (kj < myk || (kj == myk && j2 < tid)) ? 1 : 0;
                }
                s_tmp[rank] = myk;
                s_idx[rank] = tid;
                __syncthreads();
                int lane = tid & 63, wv = tid >> 6;
                float v = s_tmp[tid];
                float incl = v;
                for (int off = 1; off < 64; off <<= 1) {
                    float pp = __shfl_up(incl, off);
                    if (lane >= off) incl *= pp;
                }
                if (lane == 63) s_wk[wv] = incl;
                __syncthreads();
                float wpre = 1.f;
#pragma unroll
                for (int q = 0; q < 4; ++q) if (q < wv) wpre *= s_wk[q];
                float exin = __shfl_up(incl, 1);
                float excl = wpre * ((lane == 0) ? 1.f : exin);
                float a_s = (1.f - v) * excl;
                s_al[s_idx[tid]] = a_s;
            }
            __syncthreads();
            float ag = s_sc[4], wg = s_sc[5];
            float wwn = wg * (ag * s_al[tid] + (1.f - ag) * s_cw[tid]);
            gst(wwb + b * 256 + tid, wwn);
            s_tmp[tid] = wwn;
            __syncthreads();
            for (int s2 = 128; s2 > 0; s2 >>= 1) { if (tid < s2) s_tmp[tid] += s_tmp[tid + s2]; __syncthreads(); }
            float S = s_tmp[0];
            gst(pr_w + b * 256 + tid, (1.f - S) * gld(pr_r + b * 256 + tid) + wwn);
        } else if (bl < 80) {
            int idx = bl - 16;
            int b = idx >> 2, ks = idx & 3;
            if (tid < 64) {
                float2 v = gld2(hw + b * 512 + ks * 128 + tid * 2);
                *reinterpret_cast<float2*>(&smem[tid * 2]) = v;
            }
            __syncthreads();
            int o = tid;
            const float* wrow = W_out + o * 768 + ks * 128;
            float acc = 0;
            for (int k = 0; k < 128; k += 4) {
                float4 w4 = ld4(wrow + k);
                float4 s4 = *reinterpret_cast<const float4*>(&smem[k]);
                acc += s4.x * w4.x + s4.y * w4.y + s4.z * w4.z + s4.w * w4.w;
            }
            gst(oh + (ks * 16 + b) * 256 + o, acc);
        }
        gsync(++bseq);

        // ========== phase D: 0..127 link+bwd+fwd; 128..143 M erase/write + norms
        if (bl < 128) {
            int b = bl >> 3, ch = bl & 7;
            int ci = tid;
            float* s_wrL = smem;
            float* s_ww  = smem + 1024;
            float* s_fp  = smem + 1280;
            {
                float2 v0 = gld2(wrb + b * 1024 + tid * 4);
                float2 v1 = gld2(wrb + b * 1024 + tid * 4 + 2);
                s_wrL[tid * 4 + 0] = v0.x; s_wrL[tid * 4 + 1] = v0.y;
                s_wrL[tid * 4 + 2] = v1.x; s_wrL[tid * 4 + 3] = v1.y;
                s_ww[tid] = gld(wwb + b * 256 + tid);
            }
            __syncthreads();
            float wwc = s_ww[ci];
            float pco = gld(pr_r + b * 256 + ci);
            float* Lb = lnk + b * 65536;
            float b0 = 0, b1 = 0, b2 = 0, b3 = 0;
            int r0 = ch * 32;
            int wv = tid >> 6, lane = tid & 63;
            for (int rr = 0; rr < 32; ++rr) {
                int ri = r0 + rr;
                float wwr = s_ww[ri];
                float v = Lb[ri * 256 + ci];
                v = (1.f - wwr - wwc) * v + wwr * pco;
                if (ci == ri) v = 0.f;
                Lb[ri * 256 + ci] = v;
                b0 += v * s_wrL[ri];
                b1 += v * s_wrL[256 + ri];
                b2 += v * s_wrL[512 + ri];
                b3 += v * s_wrL[768 + ri];
                float p0 = v * s_wrL[ci];
                float p1 = v * s_wrL[256 + ci];
                float p2 = v * s_wrL[512 + ci];
                float p3 = v * s_wrL[768 + ci];
                for (int o2 = 32; o2 > 0; o2 >>= 1) {
                    p0 += __shfl_down(p0, o2); p1 += __shfl_down(p1, o2);
                    p2 += __shfl_down(p2, o2); p3 += __shfl_down(p3, o2);
                }
                if (lane == 0) {
                    s_fp[(rr * 4 + 0) * 4 + wv] = p0;
                    s_fp[(rr * 4 + 1) * 4 + wv] = p1;
                    s_fp[(rr * 4 + 2) * 4 + wv] = p2;
                    s_fp[(rr * 4 + 3) * 4 + wv] = p3;
                }
            }
            __syncthreads();
            if (tid < 128) {
                int rr = tid >> 2, r = tid & 3;
                const float* fp = s_fp + (rr * 4 + r) * 4;
                gst(fwdb + b * 1024 + r * 256 + (r0 + rr), fp[0] + fp[1] + fp[2] + fp[3]);
            }
            atomicAdd(bwdb + b * 1024 + ci, b0);
            atomicAdd(bwdb + b * 1024 + 256 + ci, b1);
            atomicAdd(bwdb + b * 1024 + 512 + ci, b2);
            atomicAdd(bwdb + b * 1024 + 768 + ci, b3);
        } else {
            int b = bl - 128;
            if (tid < 32) {
                float2 v = gld2(ers + b * 64 + tid * 2);
                *reinterpret_cast<float2*>(&smem[tid * 2]) = v;
            } else if (tid < 64) {
                int q = tid - 32;
                float2 v = gld2(wvs + b * 64 + q * 2);
                *reinterpret_cast<float2*>(&smem[64 + q * 2]) = v;
            } else if (tid < 192) {
                int q = tid - 64;
                float2 v = gld2(wwb + b * 256 + q * 2);
                *reinterpret_cast<float2*>(&smem[128 + q * 2]) = v;
            }
            __syncthreads();
            int w2g = (tid & 31) * 2, ng = tid >> 5;
            for (int i = 0; i < 32; ++i) {
                int n = ng * 32 + i;
                float wwn = smem[128 + n];
                float2 m = gld2(Mb + (b * 256 + n) * 64 + w2g);
                m.x = m.x * (1.f - wwn * smem[w2g])     + wwn * smem[64 + w2g];
                m.y = m.y * (1.f - wwn * smem[w2g + 1]) + wwn * smem[64 + w2g + 1];
                gst2(Mb + (b * 256 + n) * 64 + w2g, m.x, m.y);
                float s = m.x * m.x + m.y * m.y;
                for (int o2 = 16; o2 > 0; o2 >>= 1) s += __shfl_down(s, o2, 32);
                if (w2g == 0) gst(nrm + b * 256 + n, sqrtf(s));
            }
        }
        gsync(++bseq);

        // ========== phase E: blocks 0..63 (M staged transposed+rotated; LDS dot + PV)
        if (bl < 64) {
            int b = bl >> 2, r = bl & 3;
            for (int i = tid; i < 8192; i += BT) {
                int n = i >> 5, w2 = (i & 31) * 2;
                float2 v = gld2(Mb + (b * 256 + n) * 64 + w2);
                sbig[w2 * 256 + ((n + w2) & 255)] = v.x;
                sbig[(w2 + 1) * 256 + ((n + w2 + 1) & 255)] = v.y;
            }
            float* s_wr  = smem;
            float* s_tmp = smem + 512;
            float* s_key = smem + 768;
            float* s_sc  = smem + 840;
            s_wr[tid] = gld(wrb + b * 1024 + r * 256 + tid);
            if (tid < 64) s_key[tid] = gld(itf + b * 471 + r * 64 + tid);
            __syncthreads();
            if (tid < 64) {
                float v = s_key[tid] * s_key[tid];
                for (int o2 = 32; o2 > 0; o2 >>= 1) v += __shfl_down(v, o2);
                if (tid == 0) s_sc[0] = sqrtf(v);
            }
            __syncthreads();
            int n = tid;
            float bwd_n = gld(bwdb + b * 1024 + r * 256 + n);
            float fwd_n = gld(fwdb + b * 1024 + r * 256 + n);
            float dot = 0.f;
            for (int w = 0; w < 64; ++w)
                dot += sbig[w * 256 + ((n + w) & 255)] * s_key[w];
            float simv = gld(rso + b * 4 + r) * dot / ((gld(nrm + b * 256 + n) + 1e-6f) * (s_sc[0] + 1e-6f));
            s_tmp[tid] = simv;
            __syncthreads();
            for (int s2 = 128; s2 > 0; s2 >>= 1) { if (tid < s2) s_tmp[tid] = fmaxf(s_tmp[tid], s_tmp[tid + s2]); __syncthreads(); }
            float mx = s_tmp[0];
            __syncthreads();
            float ex = expf(simv - mx);
            s_tmp[tid] = ex;
            __syncthreads();
            for (int s2 = 128; s2 > 0; s2 >>= 1) { if (tid < s2) s_tmp[tid] += s_tmp[tid + s2]; __syncthreads(); }
            float crv = ex / s_tmp[0];
            float mbv = gld(mds + (b * 4 + r) * 3 + 0);
            float mfv = gld(mds + (b * 4 + r) * 3 + 1);
            float mcv = gld(mds + (b * 4 + r) * 3 + 2);
            float wrn = mbv * bwd_n + mfv * fwd_n + mcv * crv;
            gst(wrb + b * 1024 + r * 256 + n, wrn);
            __syncthreads();
            s_wr[tid] = wrn;
            __syncthreads();
            int w = tid & 63, gq = tid >> 6;
            float pacc = 0.f;
            for (int k = 0; k < 64; ++k) {
                int n2 = gq * 64 + k;
                pacc += s_wr[n2] * sbig[w * 256 + ((n2 + w) & 255)];
            }
            s_tmp[tid] = pacc;
            __syncthreads();
            if (tid < 64)
                gst(rwb + b * 256 + r * 64 + tid,
                    s_tmp[tid] + s_tmp[tid + 64] + s_tmp[tid + 128] + s_tmp[tid + 192]);
        }
        gsync(++bseq);
    }

    // ========== final out[T-1]: blocks 0..15
    if (bl < 16) {
        int b = bl;
        if (tid < 128) {
            float2 v = gld2(rwb + b * 256 + tid * 2);
            *reinterpret_cast<float2*>(&smem[tid * 2]) = v;
        }
        __syncthreads();
        int o = tid;
        float acc = b_out[o];
        acc += gld(oh + b * 256 + o) + gld(oh + (16 + b) * 256 + o)
             + gld(oh + (32 + b) * 256 + o) + gld(oh + (48 + b) * 256 + o);
        const float* wrow = W_out + o * 768 + 512;
        for (int k = 0; k < 256; k += 4) {
            float4 w4 = ld4(wrow + k);
            float4 s4 = *reinterpret_cast<const float4*>(&smem[k]);
            acc += s4.x * w4.x + s4.y * w4.y + s4.z * w4.z + s4.w * w4.w;
        }
        outp[((size_t)(Tt - 1) * Bx + b) * 256 + o] = acc;
    }
}

extern "C" void kernel_launch(void* const* d_in, const int* in_sizes, int n_in,
                              void* d_out, int out_size, void* d_ws, size_t ws_size,
                              hipStream_t stream) {
    const float* x     = (const float*)d_in[0];
    const float* W_ih  = (const float*)d_in[1];
    const float* W_hh  = (const float*)d_in[2];
    const float* b_ih  = (const float*)d_in[3];
    const float* b_hh  = (const float*)d_in[4];
    const float* W_int = (const float*)d_in[5];
    const float* b_int = (const float*)d_in[6];
    const float* W_out = (const float*)d_in[7];
    const float* b_out = (const float*)d_in[8];
    float* outp = (float*)d_out;
    float* ws   = (float*)d_ws;
    (void)in_sizes; (void)n_in; (void)out_size; (void)ws_size;

    k_dnc<<<GRID, BT, 0, stream>>>(x, W_ih, W_hh, b_ih, b_hh, W_int, b_int,
                                   W_out, b_out, outp, ws);
}

// Round 20
// 8942.115 us; speedup vs baseline: 1.4412x; 1.4412x over previous
//
#include <hip/hip_runtime.h>
#include <math.h>

#define BT 256
#define GRID 144

// Problem constants: B=16, T=64, IN=256, H=512, N=256, W=64, R=4, NW=1, OUT=256
#define Bx 16
#define Tt 64

__device__ __forceinline__ float sigm(float v) { return 1.0f / (1.0f + expf(-v)); }
__device__ __forceinline__ float oneplusf(float v) { return 1.0f + ((v > 15.0f) ? v : log1pf(expf(v))); }
__device__ __forceinline__ float4 ld4(const float* p) { return *reinterpret_cast<const float4*>(p); }
__device__ __forceinline__ float2 ld2f(const float* p) { return *reinterpret_cast<const float2*>(p); }

// ---- agent-scope (MALL-coherent) accessors for cross-block data ----
// Round-14 measurement: XCD L2s are NOT coherent (normal cached cross-block
// traffic fails correctness). These atomics are REQUIRED for cross-block data.
#define SCOPE_A __HIP_MEMORY_SCOPE_AGENT
__device__ __forceinline__ float gld(const float* p) {
    return __hip_atomic_load(p, __ATOMIC_RELAXED, SCOPE_A);
}
__device__ __forceinline__ void gst(float* p, float v) {
    __hip_atomic_store(p, v, __ATOMIC_RELAXED, SCOPE_A);
}
__device__ __forceinline__ float2 gld2(const float* p) {
    union { unsigned long long u; float2 f; } c;
    c.u = __hip_atomic_load(reinterpret_cast<const unsigned long long*>(p), __ATOMIC_RELAXED, SCOPE_A);
    return c.f;
}
__device__ __forceinline__ void gst2(float* p, float a, float b2) {
    union { unsigned long long u; float2 f; } c;
    c.f.x = a; c.f.y = b2;
    __hip_atomic_store(reinterpret_cast<unsigned long long*>(p), c.u, __ATOMIC_RELAXED, SCOPE_A);
}
__device__ __forceinline__ unsigned gldU(const unsigned* p) {
    return __hip_atomic_load(p, __ATOMIC_RELAXED, SCOPE_A);
}
__device__ __forceinline__ void gstU(unsigned* p, unsigned v) {
    __hip_atomic_store(p, v, __ATOMIC_RELAXED, SCOPE_A);
}

// ---- contention-free monotonic flag barrier; flags and gen on separate lines ----
__device__ __attribute__((aligned(128))) unsigned int g_flags[GRID];
__device__ __attribute__((aligned(128))) unsigned int g_gen = 0;

__device__ __forceinline__ void gsync(unsigned tgt) {
    asm volatile("" ::: "memory");
    __builtin_amdgcn_s_waitcnt(0);
    __syncthreads();
    const int tid = threadIdx.x;
    if (blockIdx.x == 0) {
        if (tid < GRID) {
            if (tid == 0) gstU(&g_flags[0], tgt);
            while (gldU(&g_flags[tid]) < tgt) __builtin_amdgcn_s_sleep(1);
        }
        __syncthreads();
        if (tid == 0) gstU(&g_gen, tgt);
    } else {
        if (tid == 0) {
            gstU(&g_flags[blockIdx.x], tgt);
            while (gldU(&g_gen) < tgt) __builtin_amdgcn_s_sleep(1);
        }
        __syncthreads();
    }
    asm volatile("" ::: "memory");
}

// ---- workspace layout (float offsets) — identical to round 5/7 ----
#define ZERO_FLOATS 1376256

__global__ __launch_bounds__(BT)
void k_dnc(const float* __restrict__ x,
           const float* __restrict__ W_ih, const float* __restrict__ W_hh,
           const float* __restrict__ b_ih, const float* __restrict__ b_hh,
           const float* __restrict__ W_int, const float* __restrict__ b_int,
           const float* __restrict__ W_out, const float* __restrict__ b_out,
           float* __restrict__ outp, float* __restrict__ ws)
{
    const int bl = blockIdx.x, tid = threadIdx.x;

    float* h0   = ws;
    float* h1   = ws + 8192;
    float* cst  = ws + 16384;    // block-private
    float* Mb   = ws + 24576;    // agent
    float* usg  = ws + 286720;   // block-private (C-blocks)
    float* lnk  = ws + 290816;   // private to D-link blocks (normal cached, L2)
    float* pr0  = ws + 1339392;
    float* pr1  = ws + 1343488;
    float* wrb  = ws + 1347584;
    float* wwb  = ws + 1363968;
    float* rwb  = ws + 1368064;
    float* nrm  = ws + 1372160;
    float* itf  = ws + 1376256;
    float* ers  = ws + 1383792;
    float* wvs  = ws + 1384816;
    float* rso  = ws + 1385840;
    float* mds  = ws + 1385904;
    float* oh   = ws + 1386096;
    float* bwdb = ws + 1402480;
    float* fwdb = ws + 1418864;

    __shared__ __align__(16) float sbig[16576];
    __shared__ __align__(16) float smem[4096];
    __shared__ int s_idx[256];
    __shared__ unsigned s_base;

    if (tid == 0) s_base = gldU(&g_gen);
    __syncthreads();
    unsigned bseq = s_base;

    for (int i = bl * BT + tid; i < ZERO_FLOATS; i += GRID * BT) gst(ws + i, 0.0f);
    gsync(++bseq);

    for (int t = 0; t < Tt; ++t) {
        const float* hr = (t & 1) ? h1 : h0;
        float*       hw = (t & 1) ? h0 : h1;
        const float* pr_r = (t & 1) ? pr1 : pr0;
        float*       pr_w = (t & 1) ? pr0 : pr1;

        // ========== phase A: blocks 0..127 gates GEMM + LSTM; 128..143 finish out[t-1]
        if (bl < 128) {
            {
                const float* xb = x + (size_t)t * (Bx * 256);
                for (int i = tid; i < 2048; i += BT) {
                    int b2 = i >> 7, q = (i & 127) * 2;
                    float2 v = ld2f(xb + b2 * 256 + q);
                    *reinterpret_cast<float2*>(&sbig[b2 * 260 + q]) = v;
                }
                for (int i = tid; i < 2048; i += BT) {
                    int b2 = i >> 7, q = (i & 127) * 2;
                    float2 v = gld2(rwb + b2 * 256 + q);
                    *reinterpret_cast<float2*>(&sbig[4160 + b2 * 260 + q]) = v;
                }
                for (int i = tid; i < 4096; i += BT) {
                    int b2 = i >> 8, q = (i & 255) * 2;
                    float2 v = gld2(hr + b2 * 512 + q);
                    *reinterpret_cast<float2*>(&sbig[8320 + b2 * 516 + q]) = v;
                }
            }
            __syncthreads();
            float* red = smem;
            int pl = tid >> 2, ks = tid & 3;
            int p = bl * 64 + pl;
            int b = p & 15, j = p >> 4;
            const float *w0, *w1, *w2, *w3;
            int kofs = (ks < 2) ? ks * 256 : (ks - 2) * 256;
            if (ks < 2) {
                w0 = W_ih + (j)        * 512 + kofs;
                w1 = W_ih + (j + 512)  * 512 + kofs;
                w2 = W_ih + (j + 1024) * 512 + kofs;
                w3 = W_ih + (j + 1536) * 512 + kofs;
            } else {
                w0 = W_hh + (j)        * 512 + kofs;
                w1 = W_hh + (j + 512)  * 512 + kofs;
                w2 = W_hh + (j + 1024) * 512 + kofs;
                w3 = W_hh + (j + 1536) * 512 + kofs;
            }
            const float* s = (ks == 0) ? &sbig[b * 260]
                           : (ks == 1) ? &sbig[4160 + b * 260]
                           :             &sbig[8320 + b * 516 + (ks - 2) * 256];
            float a0 = 0, a1 = 0, a2 = 0, a3 = 0;
            for (int kk = 0; kk < 256; kk += 4) {
                float4 iv = *reinterpret_cast<const float4*>(s + kk);
                float4 q0 = ld4(w0 + kk);
                a0 += iv.x * q0.x + iv.y * q0.y + iv.z * q0.z + iv.w * q0.w;
                float4 q1 = ld4(w1 + kk);
                a1 += iv.x * q1.x + iv.y * q1.y + iv.z * q1.z + iv.w * q1.w;
                float4 q2 = ld4(w2 + kk);
                a2 += iv.x * q2.x + iv.y * q2.y + iv.z * q2.z + iv.w * q2.w;
                float4 q3 = ld4(w3 + kk);
                a3 += iv.x * q3.x + iv.y * q3.y + iv.z * q3.z + iv.w * q3.w;
            }
            __syncthreads();
            red[pl * 16 + 0 * 4 + ks] = a0;
            red[pl * 16 + 1 * 4 + ks] = a1;
            red[pl * 16 + 2 * 4 + ks] = a2;
            red[pl * 16 + 3 * 4 + ks] = a3;
            __syncthreads();
            if (ks == 0) {
                const float* rp = red + pl * 16;
                float gi = rp[0]  + rp[1]  + rp[2]  + rp[3]  + b_ih[j]        + b_hh[j];
                float gf = rp[4]  + rp[5]  + rp[6]  + rp[7]  + b_ih[j + 512]  + b_hh[j + 512];
                float gg = rp[8]  + rp[9]  + rp[10] + rp[11] + b_ih[j + 1024] + b_hh[j + 1024];
                float go = rp[12] + rp[13] + rp[14] + rp[15] + b_ih[j + 1536] + b_hh[j + 1536];
                float cv = cst[b * 512 + j];
                cv = sigm(gf) * cv + sigm(gi) * tanhf(gg);
                float hv = sigm(go) * tanhf(cv);
                cst[b * 512 + j] = cv;
                gst(hw + b * 512 + j, hv);
            }
        } else if (t > 0) {
            int b = bl - 128;
            if (tid < 128) {
                float2 v = gld2(rwb + b * 256 + tid * 2);
                *reinterpret_cast<float2*>(&smem[tid * 2]) = v;
            }
            __syncthreads();
            int o = tid;
            float acc = b_out[o];
            acc += gld(oh + b * 256 + o) + gld(oh + (16 + b) * 256 + o)
                 + gld(oh + (32 + b) * 256 + o) + gld(oh + (48 + b) * 256 + o);
            const float* wrow = W_out + o * 768 + 512;
            for (int k = 0; k < 256; k += 4) {
                float4 w4 = ld4(wrow + k);
                float4 s4 = *reinterpret_cast<const float4*>(&smem[k]);
                acc += s4.x * w4.x + s4.y * w4.y + s4.z * w4.z + s4.w * w4.w;
            }
            outp[((size_t)(t - 1) * Bx + b) * 256 + o] = acc;
        }
        gsync(++bseq);

        // ========== phase B: blocks 0..14 itf (h staged flat); 15..78 oh partials
        if (bl < 15) {
            for (int i = tid; i < 4096; i += BT) {
                int b2 = i >> 8, q = (i & 255) * 2;
                float2 v = gld2(hw + b2 * 512 + q);
                *reinterpret_cast<float2*>(&sbig[b2 * 512 + q]) = v;
            }
            __syncthreads();
            int jl = tid & 31, k8 = tid >> 5;
            int j = bl * 32 + jl;
            float acc[16];
#pragma unroll
            for (int b = 0; b < 16; b++) acc[b] = 0.f;
            if (j < 471) {
                for (int k = k8 * 64; k < k8 * 64 + 64; ++k) {
                    float wv = W_int[k * 471 + j];
#pragma unroll
                    for (int b = 0; b < 16; b++) acc[b] += sbig[b * 512 + k] * wv;
                }
            }
            __syncthreads();
#pragma unroll
            for (int b = 0; b < 16; b++) smem[tid * 16 + b] = acc[b];
            __syncthreads();
            int jl2 = tid & 31, bh = tid >> 5;
            int j2 = bl * 32 + jl2;
            for (int rep = 0; rep < 2; ++rep) {
                int b2 = bh + 8 * rep;
                if (j2 < 471) {
                    float s = 0;
#pragma unroll
                    for (int ksx = 0; ksx < 8; ksx++) s += smem[(ksx * 32 + jl2) * 16 + b2];
                    gst(itf + b2 * 471 + j2, s + b_int[j2]);
                }
            }
        } else if (bl < 79) {
            int idx = bl - 15;
            int b = idx >> 2, ks = idx & 3;
            if (tid < 64) {
                float2 v = gld2(hw + b * 512 + ks * 128 + tid * 2);
                *reinterpret_cast<float2*>(&smem[tid * 2]) = v;
            }
            __syncthreads();
            int o = tid;
            const float* wrow = W_out + o * 768 + ks * 128;
            float acc = 0;
            for (int k = 0; k < 128; k += 4) {
                float4 w4 = ld4(wrow + k);
                float4 s4 = *reinterpret_cast<const float4*>(&smem[k]);
                acc += s4.x * w4.x + s4.y * w4.y + s4.z * w4.z + s4.w * w4.w;
            }
            gst(oh + (ks * 16 + b) * 256 + o, acc);
        }
        gsync(++bseq);

        // ========== phase C: blocks 0..15 (M staged transposed+rotated in sbig)
        if (bl < 16) {
            const int b = bl;
            for (int i = tid; i < 8192; i += BT) {
                int n = i >> 5, w2 = (i & 31) * 2;
                float2 v = gld2(Mb + (b * 256 + n) * 64 + w2);
                sbig[w2 * 256 + ((n + w2) & 255)] = v.x;
                sbig[(w2 + 1) * 256 + ((n + w2 + 1) & 255)] = v.y;
            }
            float* s_keys = smem;
            float* s_cw   = smem + 256;
            float* s_al   = smem + 512;
            float* s_tmp  = smem + 768;
            float* s_wk   = smem + 1024;
            float* s_sc   = smem + 1088;
            const float* it = itf + b * 471;

            gst(bwdb + b * 1024 + tid, 0.f);
            gst(bwdb + b * 1024 + 256 + tid, 0.f);
            gst(bwdb + b * 1024 + 512 + tid, 0.f);
            gst(bwdb + b * 1024 + 768 + tid, 0.f);

            if (tid < 4) {
                float m0 = gld(it + 459 + tid * 3), m1 = gld(it + 460 + tid * 3), m2 = gld(it + 461 + tid * 3);
                float mx3 = fmaxf(m0, fmaxf(m1, m2));
                float e0 = expf(m0 - mx3), e1 = expf(m1 - mx3), e2 = expf(m2 - mx3);
                float inv = 1.f / (e0 + e1 + e2);
                gst(mds + (b * 4 + tid) * 3 + 0, e0 * inv);
                gst(mds + (b * 4 + tid) * 3 + 1, e1 * inv);
                gst(mds + (b * 4 + tid) * 3 + 2, e2 * inv);
                gst(rso + b * 4 + tid, oneplusf(gld(it + 256 + tid)));
                s_sc[tid] = sigm(gld(it + 453 + tid));
            }
            if (tid == 4) s_sc[4] = sigm(gld(it + 457));
            if (tid == 5) s_sc[5] = sigm(gld(it + 458));
            if (tid == 6) s_sc[6] = oneplusf(gld(it + 324));
            if (tid < 64) {
                gst(ers + b * 64 + tid, sigm(gld(it + 325 + tid)));
                gst(wvs + b * 64 + tid, sigm(gld(it + 389 + tid)));
                s_wk[tid] = gld(it + 260 + tid);
            }
            __syncthreads();
            if (tid < 64) {
                float v = s_wk[tid] * s_wk[tid];
                for (int o2 = 32; o2 > 0; o2 >>= 1) v += __shfl_down(v, o2);
                if (tid == 0) s_sc[7] = sqrtf(v);
            }
            __syncthreads();
            {
                int n = tid;
                float psi = 1.f;
#pragma unroll
                for (int r = 0; r < 4; r++) psi *= (1.f - s_sc[r] * gld(wrb + b * 1024 + r * 256 + n));
                float wwp = gld(wwb + b * 256 + n);
                float u = usg[b * 256 + n];
                u = (u + wwp - u * wwp) * psi;
                usg[b * 256 + n] = u;
                s_keys[n] = u;
                float dot = 0.f;
                for (int w = 0; w < 64; ++w)
                    dot += sbig[w * 256 + ((n + w) & 255)] * s_wk[w];
                s_cw[n] = s_sc[6] * dot / ((gld(nrm + b * 256 + n) + 1e-6f) * (s_sc[7] + 1e-6f));
            }
            __syncthreads();
            s_tmp[tid] = s_cw[tid];
            __syncthreads();
            for (int s2 = 128; s2 > 0; s2 >>= 1) { if (tid < s2) s_tmp[tid] = fmaxf(s_tmp[tid], s_tmp[tid + s2]); __syncthreads(); }
            float mx = s_tmp[0];
            __syncthreads();
            float ex = expf(s_cw[tid] - mx);
            s_tmp[tid] = ex;
            __syncthreads();
            for (int s2 = 128; s2 > 0; s2 >>= 1) { if (tid < s2) s_tmp[tid] += s_tmp[tid + s2]; __syncthreads(); }
            float cwv = ex / s_tmp[0];
            __syncthreads();
            s_cw[tid] = cwv;

            // stable argsort via rank-by-counting + wave shfl prefix-product
            // (verified correct in round 10; replaces bitonic's ~70 serial barriers with 3)
            {
                float myk = s_keys[tid];
                __syncthreads();
                int rank = 0;
                for (int j2 = 0; j2 < 256; ++j2) {
                    float kj = s_keys[j2];
                    rank += (kj < myk || (kj == myk && j2 < tid)) ? 1 : 0;
                }
                s_tmp[rank] = myk;     // sorted keys ascending
                s_idx[rank] = tid;     // original index at sorted position
                __syncthreads();
                int lane = tid & 63, wv = tid >> 6;
                float v = s_tmp[tid];
                float incl = v;
                for (int off = 1; off < 64; off <<= 1) {
                    float pp = __shfl_up(incl, off);
                    if (lane >= off) incl *= pp;
                }
                if (lane == 63) s_wk[wv] = incl;   // wave totals (s_wk free now)
                __syncthreads();
                float wpre = 1.f;
#pragma unroll
                for (int q = 0; q < 4; ++q) if (q < wv) wpre *= s_wk[q];
                float exin = __shfl_up(incl, 1);
                float excl = wpre * ((lane == 0) ? 1.f : exin);
                float a_s = (1.f - v) * excl;
                s_al[s_idx[tid]] = a_s;
            }
            __syncthreads();
            float ag = s_sc[4], wg = s_sc[5];
            float wwn = wg * (ag * s_al[tid] + (1.f - ag) * s_cw[tid]);
            gst(wwb + b * 256 + tid, wwn);
            s_tmp[tid] = wwn;
            __syncthreads();
            for (int s2 = 128; s2 > 0; s2 >>= 1) { if (tid < s2) s_tmp[tid] += s_tmp[tid + s2]; __syncthreads(); }
            float S = s_tmp[0];
            gst(pr_w + b * 256 + tid, (1.f - S) * gld(pr_r + b * 256 + tid) + wwn);
        }
        gsync(++bseq);

        // ========== phase D: 0..127 link+bwd+fwd; 128..143 M erase/write + norms
        if (bl < 128) {
            int b = bl >> 3, ch = bl & 7;
            int ci = tid;
            float* s_wrL = smem;
            float* s_ww  = smem + 1024;
            float* s_fp  = smem + 1280;
            {
                float2 v0 = gld2(wrb + b * 1024 + tid * 4);
                float2 v1 = gld2(wrb + b * 1024 + tid * 4 + 2);
                s_wrL[tid * 4 + 0] = v0.x; s_wrL[tid * 4 + 1] = v0.y;
                s_wrL[tid * 4 + 2] = v1.x; s_wrL[tid * 4 + 3] = v1.y;
                s_ww[tid] = gld(wwb + b * 256 + tid);
            }
            __syncthreads();
            float wwc = s_ww[ci];
            float pco = gld(pr_r + b * 256 + ci);
            float* Lb = lnk + b * 65536;
            float b0 = 0, b1 = 0, b2 = 0, b3 = 0;
            int r0 = ch * 32;
            int wv = tid >> 6, lane = tid & 63;
            for (int rr = 0; rr < 32; ++rr) {
                int ri = r0 + rr;
                float wwr = s_ww[ri];
                float v = Lb[ri * 256 + ci];
                v = (1.f - wwr - wwc) * v + wwr * pco;
                if (ci == ri) v = 0.f;
                Lb[ri * 256 + ci] = v;
                b0 += v * s_wrL[ri];
                b1 += v * s_wrL[256 + ri];
                b2 += v * s_wrL[512 + ri];
                b3 += v * s_wrL[768 + ri];
                float p0 = v * s_wrL[ci];
                float p1 = v * s_wrL[256 + ci];
                float p2 = v * s_wrL[512 + ci];
                float p3 = v * s_wrL[768 + ci];
                for (int o2 = 32; o2 > 0; o2 >>= 1) {
                    p0 += __shfl_down(p0, o2); p1 += __shfl_down(p1, o2);
                    p2 += __shfl_down(p2, o2); p3 += __shfl_down(p3, o2);
                }
                if (lane == 0) {
                    s_fp[(rr * 4 + 0) * 4 + wv] = p0;
                    s_fp[(rr * 4 + 1) * 4 + wv] = p1;
                    s_fp[(rr * 4 + 2) * 4 + wv] = p2;
                    s_fp[(rr * 4 + 3) * 4 + wv] = p3;
                }
            }
            __syncthreads();
            if (tid < 128) {
                int rr = tid >> 2, r = tid & 3;
                const float* fp = s_fp + (rr * 4 + r) * 4;
                gst(fwdb + b * 1024 + r * 256 + (r0 + rr), fp[0] + fp[1] + fp[2] + fp[3]);
            }
            atomicAdd(bwdb + b * 1024 + ci, b0);
            atomicAdd(bwdb + b * 1024 + 256 + ci, b1);
            atomicAdd(bwdb + b * 1024 + 512 + ci, b2);
            atomicAdd(bwdb + b * 1024 + 768 + ci, b3);
        } else {
            int b = bl - 128;
            if (tid < 32) {
                float2 v = gld2(ers + b * 64 + tid * 2);
                *reinterpret_cast<float2*>(&smem[tid * 2]) = v;
            } else if (tid < 64) {
                int q = tid - 32;
                float2 v = gld2(wvs + b * 64 + q * 2);
                *reinterpret_cast<float2*>(&smem[64 + q * 2]) = v;
            } else if (tid < 192) {
                int q = tid - 64;
                float2 v = gld2(wwb + b * 256 + q * 2);
                *reinterpret_cast<float2*>(&smem[128 + q * 2]) = v;
            }
            __syncthreads();
            int w2g = (tid & 31) * 2, ng = tid >> 5;
            for (int i = 0; i < 32; ++i) {
                int n = ng * 32 + i;
                float wwn = smem[128 + n];
                float2 m = gld2(Mb + (b * 256 + n) * 64 + w2g);
                m.x = m.x * (1.f - wwn * smem[w2g])     + wwn * smem[64 + w2g];
                m.y = m.y * (1.f - wwn * smem[w2g + 1]) + wwn * smem[64 + w2g + 1];
                gst2(Mb + (b * 256 + n) * 64 + w2g, m.x, m.y);
                float s = m.x * m.x + m.y * m.y;
                for (int o2 = 16; o2 > 0; o2 >>= 1) s += __shfl_down(s, o2, 32);
                if (w2g == 0) gst(nrm + b * 256 + n, sqrtf(s));
            }
        }
        gsync(++bseq);

        // ========== phase E: blocks 0..63 (M staged transposed+rotated; LDS dot + PV)
        if (bl < 64) {
            int b = bl >> 2, r = bl & 3;
            for (int i = tid; i < 8192; i += BT) {
                int n = i >> 5, w2 = (i & 31) * 2;
                float2 v = gld2(Mb + (b * 256 + n) * 64 + w2);
                sbig[w2 * 256 + ((n + w2) & 255)] = v.x;
                sbig[(w2 + 1) * 256 + ((n + w2 + 1) & 255)] = v.y;
            }
            float* s_wr  = smem;
            float* s_tmp = smem + 512;
            float* s_key = smem + 768;
            float* s_sc  = smem + 840;
            s_wr[tid] = gld(wrb + b * 1024 + r * 256 + tid);
            if (tid < 64) s_key[tid] = gld(itf + b * 471 + r * 64 + tid);
            __syncthreads();
            if (tid < 64) {
                float v = s_key[tid] * s_key[tid];
                for (int o2 = 32; o2 > 0; o2 >>= 1) v += __shfl_down(v, o2);
                if (tid == 0) s_sc[0] = sqrtf(v);
            }
            __syncthreads();
            int n = tid;
            float bwd_n = gld(bwdb + b * 1024 + r * 256 + n);
            float fwd_n = gld(fwdb + b * 1024 + r * 256 + n);
            float dot = 0.f;
            for (int w = 0; w < 64; ++w)
                dot += sbig[w * 256 + ((n + w) & 255)] * s_key[w];
            float simv = gld(rso + b * 4 + r) * dot / ((gld(nrm + b * 256 + n) + 1e-6f) * (s_sc[0] + 1e-6f));
            s_tmp[tid] = simv;
            __syncthreads();
            for (int s2 = 128; s2 > 0; s2 >>= 1) { if (tid < s2) s_tmp[tid] = fmaxf(s_tmp[tid], s_tmp[tid + s2]); __syncthreads(); }
            float mx = s_tmp[0];
            __syncthreads();
            float ex = expf(simv - mx);
            s_tmp[tid] = ex;
            __syncthreads();
            for (int s2 = 128; s2 > 0; s2 >>= 1) { if (tid < s2) s_tmp[tid] += s_tmp[tid + s2]; __syncthreads(); }
            float crv = ex / s_tmp[0];
            float mbv = gld(mds + (b * 4 + r) * 3 + 0);
            float mfv = gld(mds + (b * 4 + r) * 3 + 1);
            float mcv = gld(mds + (b * 4 + r) * 3 + 2);
            float wrn = mbv * bwd_n + mfv * fwd_n + mcv * crv;
            gst(wrb + b * 1024 + r * 256 + n, wrn);
            __syncthreads();
            s_wr[tid] = wrn;
            __syncthreads();
            int w = tid & 63, gq = tid >> 6;
            float pacc = 0.f;
            for (int k = 0; k < 64; ++k) {
                int n2 = gq * 64 + k;
                pacc += s_wr[n2] * sbig[w * 256 + ((n2 + w) & 255)];
            }
            s_tmp[tid] = pacc;
            __syncthreads();
            if (tid < 64)
                gst(rwb + b * 256 + r * 64 + tid,
                    s_tmp[tid] + s_tmp[tid + 64] + s_tmp[tid + 128] + s_tmp[tid + 192]);
        }
        gsync(++bseq);
    }

    // ========== final out[T-1]: blocks 0..15
    if (bl < 16) {
        int b = bl;
        if (tid < 128) {
            float2 v = gld2(rwb + b * 256 + tid * 2);
            *reinterpret_cast<float2*>(&smem[tid * 2]) = v;
        }
        __syncthreads();
        int o = tid;
        float acc = b_out[o];
        acc += gld(oh + b * 256 + o) + gld(oh + (16 + b) * 256 + o)
             + gld(oh + (32 + b) * 256 + o) + gld(oh + (48 + b) * 256 + o);
        const float* wrow = W_out + o * 768 + 512;
        for (int k = 0; k < 256; k += 4) {
            float4 w4 = ld4(wrow + k);
            float4 s4 = *reinterpret_cast<const float4*>(&smem[k]);
            acc += s4.x * w4.x + s4.y * w4.y + s4.z * w4.z + s4.w * w4.w;
        }
        outp[((size_t)(Tt - 1) * Bx + b) * 256 + o] = acc;
    }
}

extern "C" void kernel_launch(void* const* d_in, const int* in_sizes, int n_in,
                              void* d_out, int out_size, void* d_ws, size_t ws_size,
                              hipStream_t stream) {
    const float* x     = (const float*)d_in[0];
    const float* W_ih  = (const float*)d_in[1];
    const float* W_hh  = (const float*)d_in[2];
    const float* b_ih  = (const float*)d_in[3];
    const float* b_hh  = (const float*)d_in[4];
    const float* W_int = (const float*)d_in[5];
    const float* b_int = (const float*)d_in[6];
    const float* W_out = (const float*)d_in[7];
    const float* b_out = (const float*)d_in[8];
    float* outp = (float*)d_out;
    float* ws   = (float*)d_ws;
    (void)in_sizes; (void)n_in; (void)out_size; (void)ws_size;

    k_dnc<<<GRID, BT, 0, stream>>>(x, W_ih, W_hh, b_ih, b_hh, W_int, b_int,
                                   W_out, b_out, outp, ws);
}